// Round 1
// baseline (47.284 us; speedup 1.0000x reference)
//
#include <hip/hip_runtime.h>
#include <hip/hip_bf16.h>

#define NB 8
#define NS 4096
#define NH 1152
#define LEN 256
#define KK 4
#define F4ROW (NH / 4)   // 288

// ws layout (int32 offsets):
//   [0..7]                mult per batch  ((max_x+1)/k)
//   [8 .. 8+2047]         counts  (per b*256+seg)
//   [2056 .. 4103]        starts  (exclusive prefix, global row index)
//   [4104 .. 6151]        cursor  (scatter write positions)
//   [6152 .. 38919]       segarr  (seg index per (b,s))
//   [38920 .. 71687]      order   (row s sorted by segment)
#define WS_MULT   0
#define WS_COUNTS 8
#define WS_STARTS 2056
#define WS_CURSOR 4104
#define WS_SEG    6152
#define WS_ORDER  38920

__global__ void gvp_k1_max_zero(const int* __restrict__ patch, int* __restrict__ ws) {
    int b = blockIdx.x;
    int t = threadIdx.x;
    ws[WS_COUNTS + b * LEN + t] = 0;          // zero histogram (t in [0,256))
    int m = 0;                                 // clamped >= 0 so init 0 is safe
    const int* p = patch + (size_t)b * NS * 2;
    for (int s = t; s < NS; s += 256) {
        int x = p[2 * s];
        if (x < 0) x = 0;
        m = max(m, x);
    }
    for (int off = 32; off > 0; off >>= 1)
        m = max(m, __shfl_down(m, off, 64));
    __shared__ int sm[4];
    if ((t & 63) == 0) sm[t >> 6] = m;
    __syncthreads();
    if (t == 0) {
        int mm = max(max(sm[0], sm[1]), max(sm[2], sm[3]));
        ws[WS_MULT + b] = (mm + 1) / KK;       // max_x // k
    }
}

__global__ void gvp_k2_seg_count(const int* __restrict__ patch, int* __restrict__ ws) {
    int gs = blockIdx.x * 256 + threadIdx.x;   // [0, B*S)
    int b = gs >> 12;
    int x = patch[2 * gs];
    int y = patch[2 * gs + 1];
    if (x < 0) x = 0;
    if (y < 0) y = 0;
    int mult = ws[WS_MULT + b];
    int seg = (x >> 2) + mult * (y >> 2);      // kidx_x + (max_x//k)*kidx_y
    if (seg > LEN - 1) seg = LEN - 1;          // safety clamp (ref asserts < LEN)
    ws[WS_SEG + gs] = seg;
    atomicAdd(&ws[WS_COUNTS + (b << 8) + seg], 1);
}

__global__ void gvp_k3_scan(int* __restrict__ ws) {
    int t = threadIdx.x;                       // 256 threads, 8 counts each
    const int* counts = ws + WS_COUNTS;
    int c[8];
    int sum = 0;
    #pragma unroll
    for (int j = 0; j < 8; ++j) { c[j] = counts[t * 8 + j]; sum += c[j]; }
    __shared__ int sd[256];
    sd[t] = sum;
    __syncthreads();
    for (int off = 1; off < 256; off <<= 1) {
        int v = (t >= off) ? sd[t - off] : 0;
        __syncthreads();
        sd[t] += v;
        __syncthreads();
    }
    int base = sd[t] - sum;                    // exclusive prefix
    #pragma unroll
    for (int j = 0; j < 8; ++j) {
        ws[WS_STARTS + t * 8 + j] = base;
        ws[WS_CURSOR + t * 8 + j] = base;
        base += c[j];
    }
}

__global__ void gvp_k4_scatter(int* __restrict__ ws) {
    int gs = blockIdx.x * 256 + threadIdx.x;
    int b = gs >> 12;
    int seg = ws[WS_SEG + gs];
    int pos = atomicAdd(&ws[WS_CURSOR + (b << 8) + seg], 1);
    ws[WS_ORDER + pos] = gs & (NS - 1);        // s within batch; pos lands in b's range
}

__global__ void gvp_k5_gather(const float* __restrict__ hidden,
                              const int* __restrict__ ws,
                              float* __restrict__ out,
                              float* __restrict__ maskout) {
    __shared__ int rows[NS];                   // worst case: all rows in one segment
    int g = blockIdx.x;                        // b*256 + seg
    int b = g >> 8;
    int t = threadIdx.x;
    int start = ws[WS_STARTS + g];
    int cnt   = ws[WS_COUNTS + g];
    for (int i = t; i < cnt; i += 256) rows[i] = ws[WS_ORDER + start + i];
    __syncthreads();

    float4 a0 = make_float4(0.f, 0.f, 0.f, 0.f);
    float4 a1 = make_float4(0.f, 0.f, 0.f, 0.f);
    const float* hb = hidden + (size_t)b * NS * NH;
    for (int r = 0; r < cnt; ++r) {
        const float4* row = (const float4*)(hb + (size_t)rows[r] * NH);
        float4 v0 = row[t];
        a0.x += v0.x; a0.y += v0.y; a0.z += v0.z; a0.w += v0.w;
        if (t < F4ROW - 256) {                 // 288 float4 / 256 threads
            float4 v1 = row[t + 256];
            a1.x += v1.x; a1.y += v1.y; a1.z += v1.z; a1.w += v1.w;
        }
    }
    const float scale = 2.1213203435596424f;   // sqrt(1152) / 16
    float4* og = (float4*)(out + (size_t)g * NH);
    og[t] = make_float4(a0.x * scale, a0.y * scale, a0.z * scale, a0.w * scale);
    if (t < F4ROW - 256)
        og[t + 256] = make_float4(a1.x * scale, a1.y * scale, a1.z * scale, a1.w * scale);
    if (t == 0) maskout[g] = (cnt > 0) ? 1.0f : 0.0f;
}

extern "C" void kernel_launch(void* const* d_in, const int* in_sizes, int n_in,
                              void* d_out, int out_size, void* d_ws, size_t ws_size,
                              hipStream_t stream) {
    const float* hidden = (const float*)d_in[0];
    const int*   patch  = (const int*)d_in[1];
    // d_in[2] (padding_positions) is unused: S != LENGTH branch.
    float* out = (float*)d_out;
    float* maskout = out + (size_t)NB * LEN * NH;   // tuple: pooled then mask
    int* ws = (int*)d_ws;

    gvp_k1_max_zero <<<NB,            256, 0, stream>>>(patch, ws);
    gvp_k2_seg_count<<<NB * NS / 256, 256, 0, stream>>>(patch, ws);
    gvp_k3_scan     <<<1,             256, 0, stream>>>(ws);
    gvp_k4_scatter  <<<NB * NS / 256, 256, 0, stream>>>(ws);
    gvp_k5_gather   <<<NB * LEN,      256, 0, stream>>>(hidden, ws, out, maskout);
}

// Round 2
// 38.288 us; speedup vs baseline: 1.2350x; 1.2350x over previous
//
#include <hip/hip_runtime.h>
#include <hip/hip_bf16.h>

#define NB 8
#define NS 4096
#define NH 1152
#define LEN 256
#define KK 4
#define F4ROW (NH / 4)   // 288

// ws layout (int32 offsets):
//   [0 .. 2047]        counts  (per b*256+seg)
//   [2048 .. 4095]     starts  (global row index into ORDER)
//   [4096 .. 36863]    order   (row s-within-batch, sorted by segment; b*NS block each)
#define WS_COUNTS 0
#define WS_STARTS 2048
#define WS_ORDER  4096

// One block per batch: max(x) -> seg per row -> histogram -> scan -> scatter.
__global__ void gvp_prep(const int* __restrict__ patch, int* __restrict__ ws,
                         float* __restrict__ maskout) {
    int b = blockIdx.x;
    int t = threadIdx.x;                       // 256 threads
    __shared__ int s_seg[NS];                  // 16 KB
    __shared__ int s_cnt[LEN];
    __shared__ int s_cur[LEN];
    __shared__ int sd[LEN];
    __shared__ int s_max[4];
    __shared__ int s_mult;

    const int2* p2 = (const int2*)(patch + (size_t)b * NS * 2);
    int xs[16], ys[16];
    int m = 0;
    #pragma unroll
    for (int i = 0; i < 16; ++i) {
        int s = t + 256 * i;
        int2 v = p2[s];
        int x = v.x < 0 ? 0 : v.x;
        int y = v.y < 0 ? 0 : v.y;
        xs[i] = x; ys[i] = y;
        m = max(m, x);
    }
    #pragma unroll
    for (int off = 32; off > 0; off >>= 1)
        m = max(m, __shfl_down(m, off, 64));
    if ((t & 63) == 0) s_max[t >> 6] = m;
    s_cnt[t] = 0;
    __syncthreads();
    if (t == 0) {
        int mm = max(max(s_max[0], s_max[1]), max(s_max[2], s_max[3]));
        s_mult = (mm + 1) >> 2;                // (max_x + 1) // k
    }
    __syncthreads();
    int mult = s_mult;

    #pragma unroll
    for (int i = 0; i < 16; ++i) {
        int seg = (xs[i] >> 2) + mult * (ys[i] >> 2);
        if (seg > LEN - 1) seg = LEN - 1;      // safety (ref guarantees < LEN)
        s_seg[t + 256 * i] = seg;
        atomicAdd(&s_cnt[seg], 1);
    }
    __syncthreads();

    int c = s_cnt[t];
    sd[t] = c;
    __syncthreads();
    for (int off = 1; off < 256; off <<= 1) {  // Hillis-Steele inclusive scan
        int v = (t >= off) ? sd[t - off] : 0;
        __syncthreads();
        sd[t] += v;
        __syncthreads();
    }
    int base = sd[t] - c;                      // within-batch exclusive prefix
    s_cur[t] = base;
    ws[WS_STARTS + b * LEN + t] = b * NS + base;
    ws[WS_COUNTS + b * LEN + t] = c;
    maskout[b * LEN + t] = (c > 0) ? 1.0f : 0.0f;
    __syncthreads();

    #pragma unroll
    for (int i = 0; i < 16; ++i) {
        int s = t + 256 * i;
        int pos = atomicAdd(&s_cur[s_seg[s]], 1);
        ws[WS_ORDER + b * NS + pos] = s;
    }
}

__global__ void gvp_gather(const float* __restrict__ hidden,
                           const int* __restrict__ ws,
                           float* __restrict__ out) {
    __shared__ int rows[NS];                   // worst case: all rows in one segment
    int g = blockIdx.x;                        // b*256 + seg
    int b = g >> 8;
    int t = threadIdx.x;
    int start = ws[WS_STARTS + g];
    int cnt   = ws[WS_COUNTS + g];
    for (int i = t; i < cnt; i += 256) rows[i] = ws[WS_ORDER + start + i];
    __syncthreads();

    float4 a0 = make_float4(0.f, 0.f, 0.f, 0.f);
    float4 a1 = make_float4(0.f, 0.f, 0.f, 0.f);
    float4 b0 = make_float4(0.f, 0.f, 0.f, 0.f);
    float4 b1 = make_float4(0.f, 0.f, 0.f, 0.f);
    const float* hb = hidden + (size_t)b * NS * NH;
    int r = 0;
    for (; r + 1 < cnt; r += 2) {              // 2-row unroll: 2-4 loads in flight
        const float4* rowA = (const float4*)(hb + (size_t)rows[r] * NH);
        const float4* rowB = (const float4*)(hb + (size_t)rows[r + 1] * NH);
        float4 vA = rowA[t];
        float4 vB = rowB[t];
        a0.x += vA.x; a0.y += vA.y; a0.z += vA.z; a0.w += vA.w;
        b0.x += vB.x; b0.y += vB.y; b0.z += vB.z; b0.w += vB.w;
        if (t < F4ROW - 256) {
            float4 wA = rowA[t + 256];
            float4 wB = rowB[t + 256];
            a1.x += wA.x; a1.y += wA.y; a1.z += wA.z; a1.w += wA.w;
            b1.x += wB.x; b1.y += wB.y; b1.z += wB.z; b1.w += wB.w;
        }
    }
    if (r < cnt) {
        const float4* rowA = (const float4*)(hb + (size_t)rows[r] * NH);
        float4 vA = rowA[t];
        a0.x += vA.x; a0.y += vA.y; a0.z += vA.z; a0.w += vA.w;
        if (t < F4ROW - 256) {
            float4 wA = rowA[t + 256];
            a1.x += wA.x; a1.y += wA.y; a1.z += wA.z; a1.w += wA.w;
        }
    }
    a0.x += b0.x; a0.y += b0.y; a0.z += b0.z; a0.w += b0.w;
    a1.x += b1.x; a1.y += b1.y; a1.z += b1.z; a1.w += b1.w;

    const float scale = 2.1213203435596424f;   // sqrt(1152) / 16
    float4* og = (float4*)(out + (size_t)g * NH);
    og[t] = make_float4(a0.x * scale, a0.y * scale, a0.z * scale, a0.w * scale);
    if (t < F4ROW - 256)
        og[t + 256] = make_float4(a1.x * scale, a1.y * scale, a1.z * scale, a1.w * scale);
}

extern "C" void kernel_launch(void* const* d_in, const int* in_sizes, int n_in,
                              void* d_out, int out_size, void* d_ws, size_t ws_size,
                              hipStream_t stream) {
    const float* hidden = (const float*)d_in[0];
    const int*   patch  = (const int*)d_in[1];
    // d_in[2] (padding_positions) unused: S != LENGTH branch.
    float* out = (float*)d_out;
    float* maskout = out + (size_t)NB * LEN * NH;   // tuple: pooled then mask
    int* ws = (int*)d_ws;

    gvp_prep  <<<NB,       256, 0, stream>>>(patch, ws, maskout);
    gvp_gather<<<NB * LEN, 256, 0, stream>>>(hidden, ws, out);
}

// Round 3
// 31.859 us; speedup vs baseline: 1.4841x; 1.2018x over previous
//
#include <hip/hip_runtime.h>
#include <hip/hip_bf16.h>

#define NB 8
#define NS 4096
#define NH 1152
#define LEN 256
#define F4ROW (NH / 4)   // 288

// Single fused kernel. Block g = b*256 + seg owns one output row.
// Phase 1 (self-service prep, ~L2 traffic only): read this batch's 4096
// (x,y) patch coords (32 KB, shared by 256 blocks -> L2-hit), block-reduce
// max_x -> mult, recompute each position's segment, LDS-append the ~16
// positions matching this block's segment.
// Phase 2: stream-sum the matched rows (4.6 KB contiguous each), scale, store.
__global__ void gvp_fused(const float* __restrict__ hidden,
                          const int* __restrict__ patch,
                          float* __restrict__ out,
                          float* __restrict__ maskout) {
    int g = blockIdx.x;                        // b*256 + seg
    int b = g >> 8;
    int myseg = g & (LEN - 1);
    int t = threadIdx.x;                       // 256 threads

    __shared__ int rows[NS];                   // worst case: every row in one seg
    __shared__ int s_max[4];
    __shared__ int s_cnt;
    __shared__ int s_mult;
    if (t == 0) s_cnt = 0;

    const int2* p2 = (const int2*)(patch + (size_t)b * NS * 2);
    int pk[16];
    int m = 0;
    #pragma unroll
    for (int i = 0; i < 16; ++i) {             // 16 independent 8B loads, L2-hot
        int2 v = p2[t + 256 * i];
        int x = v.x < 0 ? 0 : v.x;
        int y = v.y < 0 ? 0 : v.y;
        pk[i] = x | (y << 16);                 // coords < 64: pack to 1 VGPR
        m = max(m, x);
    }
    #pragma unroll
    for (int off = 32; off > 0; off >>= 1)
        m = max(m, __shfl_down(m, off, 64));
    if ((t & 63) == 0) s_max[t >> 6] = m;
    __syncthreads();
    if (t == 0)
        s_mult = (max(max(s_max[0], s_max[1]), max(s_max[2], s_max[3])) + 1) >> 2;
    __syncthreads();
    int mult = s_mult;

    #pragma unroll
    for (int i = 0; i < 16; ++i) {
        int x = pk[i] & 0xffff;
        int y = pk[i] >> 16;
        int seg = (x >> 2) + mult * (y >> 2);  // ref guarantees < LEN
        if (seg == myseg) {
            int pos = atomicAdd(&s_cnt, 1);    // ~16 appends/block, ~0 contention
            rows[pos] = t + 256 * i;
        }
    }
    __syncthreads();
    int cnt = s_cnt;

    // Phase 2: 4-row unrolled gather. 288 float4 per row over 256 threads:
    // all threads take column t; threads t<32 also take column t+256.
    float4 a0 = make_float4(0.f, 0.f, 0.f, 0.f);
    float4 a1 = make_float4(0.f, 0.f, 0.f, 0.f);
    float4 c0 = make_float4(0.f, 0.f, 0.f, 0.f);
    float4 c1 = make_float4(0.f, 0.f, 0.f, 0.f);
    const float* hb = hidden + (size_t)b * NS * NH;
    int r = 0;
    for (; r + 3 < cnt; r += 4) {
        const float4* rA = (const float4*)(hb + (size_t)rows[r]     * NH);
        const float4* rB = (const float4*)(hb + (size_t)rows[r + 1] * NH);
        const float4* rC = (const float4*)(hb + (size_t)rows[r + 2] * NH);
        const float4* rD = (const float4*)(hb + (size_t)rows[r + 3] * NH);
        float4 vA = rA[t], vB = rB[t], vC = rC[t], vD = rD[t];
        a0.x += vA.x + vB.x; a0.y += vA.y + vB.y; a0.z += vA.z + vB.z; a0.w += vA.w + vB.w;
        c0.x += vC.x + vD.x; c0.y += vC.y + vD.y; c0.z += vC.z + vD.z; c0.w += vC.w + vD.w;
        if (t < F4ROW - 256) {
            float4 wA = rA[t + 256], wB = rB[t + 256], wC = rC[t + 256], wD = rD[t + 256];
            a1.x += wA.x + wB.x; a1.y += wA.y + wB.y; a1.z += wA.z + wB.z; a1.w += wA.w + wB.w;
            c1.x += wC.x + wD.x; c1.y += wC.y + wD.y; c1.z += wC.z + wD.z; c1.w += wC.w + wD.w;
        }
    }
    for (; r < cnt; ++r) {
        const float4* rA = (const float4*)(hb + (size_t)rows[r] * NH);
        float4 vA = rA[t];
        a0.x += vA.x; a0.y += vA.y; a0.z += vA.z; a0.w += vA.w;
        if (t < F4ROW - 256) {
            float4 wA = rA[t + 256];
            a1.x += wA.x; a1.y += wA.y; a1.z += wA.z; a1.w += wA.w;
        }
    }
    a0.x += c0.x; a0.y += c0.y; a0.z += c0.z; a0.w += c0.w;
    a1.x += c1.x; a1.y += c1.y; a1.z += c1.z; a1.w += c1.w;

    const float scale = 2.1213203435596424f;   // sqrt(1152) / 16
    float4* og = (float4*)(out + (size_t)g * NH);
    og[t] = make_float4(a0.x * scale, a0.y * scale, a0.z * scale, a0.w * scale);
    if (t < F4ROW - 256)
        og[t + 256] = make_float4(a1.x * scale, a1.y * scale, a1.z * scale, a1.w * scale);
    if (t == 0) maskout[g] = (cnt > 0) ? 1.0f : 0.0f;
}

extern "C" void kernel_launch(void* const* d_in, const int* in_sizes, int n_in,
                              void* d_out, int out_size, void* d_ws, size_t ws_size,
                              hipStream_t stream) {
    const float* hidden = (const float*)d_in[0];
    const int*   patch  = (const int*)d_in[1];
    // d_in[2] (padding_positions) unused: S != LENGTH branch.
    float* out = (float*)d_out;
    float* maskout = out + (size_t)NB * LEN * NH;   // tuple: pooled then mask

    gvp_fused<<<NB * LEN, 256, 0, stream>>>(hidden, patch, out, maskout);
}